// Round 13
// baseline (34.738 us; speedup 1.0000x reference)
//
#include <hip/hip_runtime.h>
#include <math.h>

#define MAX_T 2048
#define SEG_P 4   // segments per pool block (measured optimum: {1:40.6, 2:37.5, 4:35.3, 8:~39} µs)

typedef float f32x4 __attribute__((ext_vector_type(4)));  // native vec for NT stores

// ---------------- Kernel 1: score = sigmoid(feat . W + b) ----------------
// Grid-stride, one wave per row per trip; W fragment + bias hoisted into
// registers outside the row loop. Fast path for D=512 (n4=128: lane reads
// idx {lane, lane+64}); generic fallback otherwise.
__global__ __launch_bounds__(256) void score_kernel(
    const float* __restrict__ feat, const float* __restrict__ W,
    const float* __restrict__ bias, float* __restrict__ score,
    int nrows, int D) {
  int wid = threadIdx.x >> 6;
  int lane = threadIdx.x & 63;
  int n4 = D >> 2;
  const float4* w4 = (const float4*)W;
  float b0 = bias[0];
  int stride = gridDim.x * 4;

  if (n4 == 128) {
    float4 w0 = w4[lane];
    float4 w1 = w4[lane + 64];
    for (int row = blockIdx.x * 4 + wid; row < nrows; row += stride) {
      const float4* f4 = (const float4*)(feat + (size_t)row * 512);
      float4 a0 = f4[lane];
      float4 a1 = f4[lane + 64];
      float acc = a0.x * w0.x + a0.y * w0.y + a0.z * w0.z + a0.w * w0.w
                + a1.x * w1.x + a1.y * w1.y + a1.z * w1.z + a1.w * w1.w;
#pragma unroll
      for (int off = 32; off > 0; off >>= 1) acc += __shfl_xor(acc, off, 64);
      if (lane == 0) score[row] = 1.f / (1.f + expf(-(acc + b0)));
    }
  } else {
    for (int row = blockIdx.x * 4 + wid; row < nrows; row += stride) {
      const float4* f4 = (const float4*)(feat + (size_t)row * D);
      float acc = 0.f;
      for (int idx = lane; idx < n4; idx += 64) {
        float4 a = f4[idx];
        float4 w = w4[idx];
        acc += a.x * w.x + a.y * w.y + a.z * w.z + a.w * w.w;
      }
#pragma unroll
      for (int off = 32; off > 0; off >>= 1) acc += __shfl_xor(acc, off, 64);
      if (lane == 0) score[row] = 1.f / (1.f + expf(-(acc + b0)));
    }
  }
}

// ---------------- Kernel 2: valley detect -> vi table (1024 thr) --------
// One block per batch element. vi[j] = frame index of valley j.
// Atom j := [vi[j-1], vi[j]) with vi[-1]:=0 (atom 0 empty since vi[0]==0).
// Segment k = atom k U atom k+1 (k<hn-1); segment hn-1 = atom hn-1.
__global__ __launch_bounds__(1024) void seg_kernel(
    const float* __restrict__ score, const int* __restrict__ hlens,
    int* __restrict__ vi_ws, int* __restrict__ hn_ws,
    float* __restrict__ hn_out, int T, int M) {
  int b = blockIdx.x;
  int tid = threadIdx.x;
  const int NT = 1024;
  __shared__ float s[MAX_T];
  __shared__ unsigned char fl[MAX_T];
  __shared__ int vi[MAX_T];
  __shared__ int wsum[16];

  const float* sr = score + (size_t)b * T;
  int hl = hlens[b];

  for (int t = tid; t < T; t += NT) s[t] = sr[t];
  __syncthreads();

  for (int t = tid; t < T; t += NT) {
    bool f;
    if (t >= hl)                     f = false;
    else if (t == 0 || t == hl - 1)  f = true;
    else {
      float c = s[t];
      f = (c >= s[t - 1]) && (c >= s[t + 1]);
    }
    fl[t] = f ? (unsigned char)1 : (unsigned char)0;
  }
  __syncthreads();

  int C = (T + NT - 1) / NT;            // 2
  int lo = tid * C;
  int hi = lo + C; if (hi > T) hi = T; if (lo > T) lo = T;
  int cnt = 0;
  for (int t = lo; t < hi; ++t) cnt += fl[t];

  int lane = tid & 63, wid = tid >> 6;  // 16 waves
  int incl = cnt;
#pragma unroll
  for (int off = 1; off < 64; off <<= 1) {
    int v = __shfl_up(incl, off, 64);
    if (lane >= off) incl += v;
  }
  if (lane == 63) wsum[wid] = incl;
  __syncthreads();
  int wofs = 0, hn = 0;
#pragma unroll
  for (int w = 0; w < 16; ++w) {
    if (w < wid) wofs += wsum[w];
    hn += wsum[w];
  }
  int excl = wofs + incl - cnt;
  for (int t = lo; t < hi; ++t) {
    if (fl[t]) vi[excl++] = t;
  }
  __syncthreads();

  for (int j = tid; j < M; j += NT) {
    vi_ws[(size_t)b * M + j] = (j < hn) ? vi[j] : 0;
  }
  if (tid == 0) {
    hn_ws[b] = hn;
    hn_out[b] = (float)hn;
  }
}

// ---------------- Kernel 3: grouped rolling-atom pool (R5 body) ---------
// One 128-thread block per SEG_P consecutive segments of one batch.
// Rolling 2-atom register window; feat read 1.25x, served mostly from L3.
// Output stores are nontemporal (write-once; keep caches for feat).
__global__ __launch_bounds__(128) void pool_kernel(
    const float* __restrict__ feat, const float* __restrict__ score,
    const int* __restrict__ vi_ws, const int* __restrict__ hn_ws,
    float* __restrict__ out, int T, int D, int M, int ngrp) {
  int gid = blockIdx.x;
  int lane = threadIdx.x;                 // 128 lanes, float4 covers D=512
  int b = gid / ngrp;
  int g = gid - b * ngrp;
  int k0 = g * SEG_P;
  if (k0 >= M) return;

  int hn = hn_ws[b];
  const int* vi = vi_ws + (size_t)b * M;
  const float* sr = score + (size_t)b * T;
  const float4* fr = (const float4*)(feat + (size_t)b * T * (size_t)D);

  int kend = k0 + SEG_P; if (kend > M) kend = M;

  auto store_nt = [&](int k, float x, float y, float z, float w) {
    f32x4 r; r.x = x; r.y = y; r.z = z; r.w = w;
    __builtin_nontemporal_store(r, (f32x4*)(out + ((size_t)b * M + k) * D) + lane);
  };

  float4 ap = make_float4(0.f, 0.f, 0.f, 0.f);
  float ssp = 0.f;
  if (k0 < hn) {
    int as = (k0 == 0) ? 0 : vi[k0 - 1];
    int ae = vi[k0];
    for (int t = as; t < ae; ++t) {
      float sc = sr[t];
      float4 f = fr[(size_t)t * 128 + lane];
      ap.x += sc * f.x; ap.y += sc * f.y; ap.z += sc * f.z; ap.w += sc * f.w;
      ssp += sc;
    }
  }

  for (int k = k0; k < kend; ++k) {
    if (k >= hn) {
      store_nt(k, 0.f, 0.f, 0.f, 0.f);
      continue;
    }
    if (k == hn - 1) {
      float inv = 1.f / (ssp + 1e-10f);
      store_nt(k, ap.x * inv, ap.y * inv, ap.z * inv, ap.w * inv);
      ssp = 0.f; ap = make_float4(0.f, 0.f, 0.f, 0.f);
      continue;
    }
    float4 ac = make_float4(0.f, 0.f, 0.f, 0.f);
    float ssc = 0.f;
    int as = vi[k];
    int ae = vi[k + 1];
    for (int t = as; t < ae; ++t) {
      float sc = sr[t];
      float4 f = fr[(size_t)t * 128 + lane];
      ac.x += sc * f.x; ac.y += sc * f.y; ac.z += sc * f.z; ac.w += sc * f.w;
      ssc += sc;
    }
    float inv = 1.f / (ssp + ssc + 1e-10f);
    store_nt(k, (ap.x + ac.x) * inv, (ap.y + ac.y) * inv,
             (ap.z + ac.z) * inv, (ap.w + ac.w) * inv);
    ap = ac; ssp = ssc;
  }
}

extern "C" void kernel_launch(void* const* d_in, const int* in_sizes, int n_in,
                              void* d_out, int out_size, void* d_ws, size_t ws_size,
                              hipStream_t stream) {
  const float* feat = (const float*)d_in[0];
  const float* W    = (const float*)d_in[1];
  const float* bias = (const float*)d_in[2];
  const int* hlens  = (const int*)d_in[3];

  int D = in_sizes[1];                 // 512
  int B = in_sizes[3];                 // 16
  int T = in_sizes[0] / (B * D);       // 2000
  int M = (out_size - B - B * T) / (B * D);  // data-dependent max segments

  float* out      = (float*)d_out;
  float* hn_out   = out + (size_t)B * M * D;      // [B] (as float)
  float* score    = hn_out + B;                   // [B, T]

  // ws layout: vi[B*M] int | hn_ws[B] int
  int* vi_ws = (int*)d_ws;
  int* hn_ws = vi_ws + (size_t)B * M;

  int nrows = B * T;
  int nblk = 2048;
  if (nblk * 4 > nrows) nblk = (nrows + 3) / 4;
  score_kernel<<<nblk, 256, 0, stream>>>(feat, W, bias, score, nrows, D);
  seg_kernel<<<B, 1024, 0, stream>>>(score, hlens, vi_ws, hn_ws, hn_out, T, M);

  int ngrp = (M + SEG_P - 1) / SEG_P;
  pool_kernel<<<B * ngrp, 128, 0, stream>>>(feat, score, vi_ws, hn_ws,
                                            out, T, D, M, ngrp);
}